// Round 2
// baseline (288.132 us; speedup 1.0000x reference)
//
#include <hip/hip_runtime.h>
#include <cstdint>
#include <cstddef>

#define M_DIM 4096
#define K_DIM 4096
#define N_DIM 11008
#define BM 256
#define BN 256
#define BKI 64                      /* K elems (bytes) per tile */
#define NT (K_DIM / BKI)            /* 64 K-tiles */
#define NTM (M_DIM / BM)            /* 16 */
#define NTN (N_DIM / BN)            /* 43 */
#define TILE_A_BYTES (BM * BKI)     /* 16384 */
#define RING_STRIDE (2 * TILE_A_BYTES) /* A+B = 32768 */
#define RING 3                      /* 96 KB LDS */

typedef int   int4v   __attribute__((ext_vector_type(4)));
typedef float float4v __attribute__((ext_vector_type(4)));

__device__ __forceinline__ void gload_lds16(const void* g, void* l) {
  __builtin_amdgcn_global_load_lds(
      (const __attribute__((address_space(1))) unsigned int*)g,
      (__attribute__((address_space(3))) unsigned int*)l, 16, 0, 0);
}

// ---------------- x quantization: fp32 -> int8 ----------------
__global__ void quant_x_kernel(const float* __restrict__ x,
                               const float* __restrict__ scale_p,
                               const int* __restrict__ off_p,
                               signed char* __restrict__ xq, int total16) {
  const float inv = 1.0f / scale_p[0];
  const float off = (float)off_p[0];
  int tid = blockIdx.x * blockDim.x + threadIdx.x;
  int stride = gridDim.x * blockDim.x;
  const float4v* x4 = (const float4v*)x;
  int4v* out4 = (int4v*)xq;
  for (int i = tid; i < total16; i += stride) {
    int4v o;
#pragma unroll
    for (int j = 0; j < 4; ++j) {
      float4v v = x4[(size_t)i * 4 + j];
      int r = 0;
#pragma unroll
      for (int e = 0; e < 4; ++e) {
        float q = rintf(v[e] * inv) + off;     // round-half-even, matches jnp.round
        q = fminf(fmaxf(q, -128.0f), 127.0f);
        int qi = (int)q;
        r |= (qi & 0xff) << (8 * e);
      }
      o[j] = r;
    }
    out4[i] = o;
  }
}

// ---------------- weight pack: int32 carrier -> int8 ----------------
__global__ void pack_w_kernel(const int* __restrict__ w,
                              signed char* __restrict__ wq, int total16) {
  int tid = blockIdx.x * blockDim.x + threadIdx.x;
  int stride = gridDim.x * blockDim.x;
  const int4v* w4 = (const int4v*)w;
  int4v* out4 = (int4v*)wq;
  for (int i = tid; i < total16; i += stride) {
    int4v o;
#pragma unroll
    for (int j = 0; j < 4; ++j) {
      int4v v = w4[(size_t)i * 4 + j];
      o[j] = (v[0] & 0xff) | ((v[1] & 0xff) << 8) |
             ((v[2] & 0xff) << 16) | ((v[3] & 0xff) << 24);
    }
    out4[i] = o;
  }
}

// ---------------- int8 GEMM, 256x256 tile, 8 waves, ring-buffered ----------------
// A: xq [M][K] int8, B: wq [N][K] int8 (B^T), out fp32 [M][N]
// LDS layout: fragment-packed. Tile = 16 A-frags + 16 B-frags of 1KB.
// Fragment f holds rows 16f..16f+15; lane l's 16B at f*1024 + l*16 is
// element [16f + (l&15)][(l>>4)*16 .. +16] of the K-slice — so every
// ds_read_b128 is base + lane*16 (contiguous, conflict-free).
__global__ __launch_bounds__(512, 2) void gemm_i8_kernel(
    const signed char* __restrict__ A,
    const signed char* __restrict__ B,
    const int* __restrict__ qbias,
    const float* __restrict__ dscale,
    float* __restrict__ out) {
  __shared__ __attribute__((aligned(16))) signed char lds[RING * RING_STRIDE];

  const int tid  = threadIdx.x;
  const int lane = tid & 63;
  const int wv   = tid >> 6;   // 0..7
  const int wr   = wv >> 2;    // 0..1  (M half)
  const int wc   = wv & 3;     // 0..3  (N quarter)

  // XCD-aware swizzle: 688 blocks, 86 per XCD, then tn-major within XCD
  int bid = blockIdx.x;
  int swz = (bid & 7) * ((NTM * NTN) >> 3) + (bid >> 3);
  int tm = swz & (NTM - 1);
  int tn = swz >> 4;           // NTM == 16

  const signed char* Ab = A + (size_t)tm * BM * K_DIM;
  const signed char* Bb = B + (size_t)tn * BN * K_DIM;

  // Staging: wave wv stages fragments 2wv and 2wv+1 of each operand.
  const int fA    = wv * 2;
  const int srow  = fA * 16 + (lane & 15);
  const int koff  = (lane >> 4) * 16;
  const signed char* gA0 = Ab + (size_t)srow * K_DIM + koff;
  const signed char* gA1 = gA0 + (size_t)16 * K_DIM;
  const signed char* gB0 = Bb + (size_t)srow * K_DIM + koff;
  const signed char* gB1 = gB0 + (size_t)16 * K_DIM;
  const int dstA = fA * 1024;                    // wave-uniform LDS offsets
  const int dstB = TILE_A_BYTES + fA * 1024;

#define STAGE_A(kt, roff) do { \
    gload_lds16(gA0 + (size_t)(kt) * BKI, lds + (roff) + dstA); \
    gload_lds16(gA1 + (size_t)(kt) * BKI, lds + (roff) + dstA + 1024); } while (0)
#define STAGE_B(kt, roff) do { \
    gload_lds16(gB0 + (size_t)(kt) * BKI, lds + (roff) + dstB); \
    gload_lds16(gB1 + (size_t)(kt) * BKI, lds + (roff) + dstB + 1024); } while (0)

  // ds_read offsets (per-thread): fragment-packed, contiguous per wave
  const int rdA = (wr * 8) * 1024 + lane * 16;               // + mi*1024
  const int rdB = TILE_A_BYTES + (wc * 4) * 1024 + lane * 16; // + ni*1024

  int4v acc[8][4];
#pragma unroll
  for (int i = 0; i < 8; ++i)
#pragma unroll
    for (int j = 0; j < 4; ++j) acc[i][j] = (int4v){0, 0, 0, 0};

  // ---- prologue: stage tiles 0 and 1, wait tile 0 (counted) ----
  STAGE_A(0, 0);
  STAGE_B(0, 0);
  STAGE_A(1, RING_STRIDE);
  STAGE_B(1, RING_STRIDE);
  asm volatile("s_waitcnt vmcnt(4)" ::: "memory");  // tile0 landed, tile1 in flight
  __builtin_amdgcn_s_barrier();

  int roff = 0;
  for (int kt = 0; kt < NT; ++kt) {
    int nxt = roff + 2 * RING_STRIDE;
    if (nxt >= RING * RING_STRIDE) nxt -= RING * RING_STRIDE;

    // ---- phase 0: B frags + A frags 0-3, prefetch A of tile kt+2 ----
    int4v bfr[4], afr[4];
#pragma unroll
    for (int ni = 0; ni < 4; ++ni)
      bfr[ni] = *(const int4v*)(lds + roff + rdB + ni * 1024);
#pragma unroll
    for (int mi = 0; mi < 4; ++mi)
      afr[mi] = *(const int4v*)(lds + roff + rdA + mi * 1024);
    if (kt + 2 < NT) STAGE_A(kt + 2, nxt);
    __builtin_amdgcn_s_barrier();
    asm volatile("s_waitcnt lgkmcnt(0)" ::: "memory");
    __builtin_amdgcn_s_setprio(1);
#pragma unroll
    for (int mi = 0; mi < 4; ++mi)
#pragma unroll
      for (int ni = 0; ni < 4; ++ni)
        acc[mi][ni] = __builtin_amdgcn_mfma_i32_16x16x64_i8(
            afr[mi], bfr[ni], acc[mi][ni], 0, 0, 0);
    __builtin_amdgcn_s_setprio(0);
    __builtin_amdgcn_s_barrier();

    // ---- phase 1: A frags 4-7, prefetch B of tile kt+2 ----
#pragma unroll
    for (int mi = 0; mi < 4; ++mi)
      afr[mi] = *(const int4v*)(lds + roff + rdA + (mi + 4) * 1024);
    if (kt + 2 < NT) STAGE_B(kt + 2, nxt);
    __builtin_amdgcn_s_barrier();
    asm volatile("s_waitcnt lgkmcnt(0)" ::: "memory");
    __builtin_amdgcn_s_setprio(1);
#pragma unroll
    for (int mi = 0; mi < 4; ++mi)
#pragma unroll
      for (int ni = 0; ni < 4; ++ni)
        acc[mi + 4][ni] = __builtin_amdgcn_mfma_i32_16x16x64_i8(
            afr[mi], bfr[ni], acc[mi + 4][ni], 0, 0, 0);
    __builtin_amdgcn_s_setprio(0);
    // counted wait: tile kt+1 must be landed; tile kt+2's 4 loads may fly
    if (kt + 2 < NT) asm volatile("s_waitcnt vmcnt(4)" ::: "memory");
    else             asm volatile("s_waitcnt vmcnt(0)" ::: "memory");
    __builtin_amdgcn_s_barrier();

    roff += RING_STRIDE;
    if (roff >= RING * RING_STRIDE) roff -= RING * RING_STRIDE;
  }
#undef STAGE_A
#undef STAGE_B

  // ---- epilogue: out[m][n] = (acc + qbias[n]) * dscale[n] ----
  const int col = lane & 15;
  const int rb  = (lane >> 4) * 4;
  const int gm0 = tm * BM + wr * 128;
  const int gn0 = tn * BN + wc * 64;
#pragma unroll
  for (int ni = 0; ni < 4; ++ni) {
    int gn = gn0 + ni * 16 + col;
    float ds = dscale[gn];
    int qb = qbias[gn];
#pragma unroll
    for (int mi = 0; mi < 8; ++mi) {
      int gm = gm0 + mi * 16 + rb;
#pragma unroll
      for (int j = 0; j < 4; ++j)
        out[(size_t)(gm + j) * N_DIM + gn] = (float)(acc[mi][ni][j] + qb) * ds;
    }
  }
}

extern "C" void kernel_launch(void* const* d_in, const int* in_sizes, int n_in,
                              void* d_out, int out_size, void* d_ws, size_t ws_size,
                              hipStream_t stream) {
  const float* x      = (const float*)d_in[0];
  const int*   w      = (const int*)d_in[1];
  const float* dscale = (const float*)d_in[2];
  const float* iscale = (const float*)d_in[3];
  const int*   ioff   = (const int*)d_in[4];
  const int*   qbias  = (const int*)d_in[5];
  float* out = (float*)d_out;

  const size_t xq_bytes = (size_t)M_DIM * K_DIM;        // 16 MB
  const size_t wq_bytes = (size_t)N_DIM * K_DIM;        // 45 MB
  if (ws_size < xq_bytes + wq_bytes) return;

  signed char* xq = (signed char*)d_ws;
  signed char* wq = (signed char*)d_ws + xq_bytes;

  quant_x_kernel<<<2048, 256, 0, stream>>>(x, iscale, ioff, xq, M_DIM * K_DIM / 16);
  pack_w_kernel<<<2048, 256, 0, stream>>>(w, wq, N_DIM * K_DIM / 16);
  gemm_i8_kernel<<<NTM * NTN, 512, 0, stream>>>(xq, wq, qbias, dscale, out);
}